// Round 4
// baseline (517.158 us; speedup 1.0000x reference)
//
#include <hip/hip_runtime.h>

using bf16x8 = __attribute__((ext_vector_type(8))) __bf16;
using bf16x4 = __attribute__((ext_vector_type(4))) __bf16;
using f32x4  = __attribute__((ext_vector_type(4))) float;

#define BM 256
#define BN 256

// Async global->LDS, 16B per lane. LDS dest is wave-uniform base + lane*16
// (m104/m108): pass the wave's base, per-lane global src.
__device__ __forceinline__ void async_load16(const void* g, void* l) {
    __builtin_amdgcn_global_load_lds(
        (const __attribute__((address_space(1))) unsigned int*)g,
        (__attribute__((address_space(3))) unsigned int*)l,
        16, 0, 0);
}

// ------------------------------------------------------------- prep kernels
// prep_x: fp32 -> bf16, unit-stride float4 per lane (16B load, 8B store).
__global__ __launch_bounds__(256) void prep_x(
    const float* __restrict__ x, __bf16* __restrict__ xb, int n4) {
    const int c = blockIdx.x * 256 + threadIdx.x;
    if (c >= n4) return;
    const float4 a = ((const float4*)x)[c];
    bf16x4 v;
    v[0] = (__bf16)a.x; v[1] = (__bf16)a.y; v[2] = (__bf16)a.z; v[3] = (__bf16)a.w;
    ((bf16x4*)xb)[c] = v;
}

// prep_w: int32 quant -> (q-128)*scale -> bf16.  2D grid: row = blockIdx.y
// (no integer division), unit-stride int4 per lane.
__global__ __launch_bounds__(256) void prep_w(
    const int* __restrict__ wq, const float* __restrict__ sc,
    __bf16* __restrict__ wb, int I) {
    const int row = blockIdx.y;
    const int c = blockIdx.x * 256 + threadIdx.x;   // [0, I/4)
    const size_t base = (size_t)row * I + (size_t)c * 4;
    const float s = sc[row * (I >> 5) + (c >> 3)];
    const int4 a = *(const int4*)(wq + base);
    bf16x4 v;
    v[0] = (__bf16)((float)(a.x - 128) * s);
    v[1] = (__bf16)((float)(a.y - 128) * s);
    v[2] = (__bf16)((float)(a.z - 128) * s);
    v[3] = (__bf16)((float)(a.w - 128) * s);
    *(bf16x4*)(wb + base) = v;
}

// ---------------------------------------------------------------- main GEMM
// C[M,N] = A[M,K]*B[N,K]^T + bias[N].  256x256 tile, BK=64, 8 waves (2Mx4N),
// 8-phase schedule (T3+T4), st-swizzled LDS (T2), setprio (T5), XCD swz (T1).
//
// LDS (128 KiB): A tiles [2][256][64]bf16 at byte 0, B tiles at byte 65536.
// Swizzle: logical (row, colbyte) stored at phys = lin ^ (((lin>>7)&7)<<4)
// (involution, 16B-chunk preserving; round-2 verified: 0 bank conflicts).
// Staging: gload_lds writes LINEAR phys; per-lane GLOBAL src pre-deswizzled.
//
// Per iteration = 2 K-tiles: buf0 = Kt(2i) in phases 0-3, buf1 = Kt(2i+1)
// in phases 4-7.  FRONT-LOADED read layout (frees regions early so staging
// can lead by 2-6 phases):
//   P0: read a[m0-7? no: m0-3] + b[n0-1] (12 rd)  MFMA m0-3 x n0-1
//   P1: read a[m4-7]            (8 rd)            MFMA m4-7 x n0-1
//   P2: read b[n2-3]            (4 rd)            MFMA m0-3 x n2-3
//   P3: (no reads)                                MFMA m4-7 x n2-3
// A half-tiles dead after P1; B half-tiles dead after P2.
// Staging: EXACTLY 1 half-tile (2 gload_lds) per phase:
//   P0: buf1.B0@k+64   (WAR: buf1.B last read prev-P6)
//   P1: buf1.B1@k+64   (WAR: same)
//   P2: buf0.A0@k+128  (WAR: buf0.A last read P1)
//   P3: buf0.A1@k+128
//   P4: buf0.B0@k+128  (WAR: buf0.B last read P2)
//   P5: buf0.B1@k+128
//   P6: buf1.A0@k+192  (WAR: buf1.A last read P5)
//   P7: buf1.A1@k+192
// Fences vmcnt(4) at P3-end (outstanding = prevP6,prevP7,P0,P1 [= Kt2i+1
// complete] + P2,P3 = 12; drains the oldest 8 = Kt2i+1 before P4 reads
// buf1) and P7-end (outstanding = P2..P7 = 12; drains P2..P5 = Kt2i+2
// before next-P0 reads buf0).  Youngest-drained slack: B 2-3 phases
// (L2-resident operand), A 5-6 phases (HBM-streaming operand).  Never
// drained to 0 in the loop.  lgkmcnt(8) pacing hint in 12-read phases
// (template).  Tail stages wrap k mod K (in-bounds, data unused).  After
// the loop: vmcnt(0) before s_endpgm (in-flight LDS-DMA at wave exit
// corrupts successor WG's LDS).
#define REGA 0
#define REGB 65536

#define BARRIER()  __builtin_amdgcn_s_barrier()
#define LGKM0()    asm volatile("s_waitcnt lgkmcnt(0)" ::: "memory")
#define LGKM8()    asm volatile("s_waitcnt lgkmcnt(8)" ::: "memory")
#define VMCNT4()   asm volatile("s_waitcnt vmcnt(4)" ::: "memory")
#define VMCNT0()   asm volatile("s_waitcnt vmcnt(0)" ::: "memory")
#define PRIO1()    __builtin_amdgcn_s_setprio(1)
#define PRIO0()    __builtin_amdgcn_s_setprio(0)

__global__ __launch_bounds__(512, 2) void gemm_8phase(
    const __bf16* __restrict__ A, const __bf16* __restrict__ B,
    const float* __restrict__ bias, float* __restrict__ C,
    int M, int N, int K) {
    __shared__ char lds[131072] __attribute__((aligned(16)));
    char* const ldsb = lds;

    const int tid  = threadIdx.x;
    const int wave = tid >> 6;
    const int lane = tid & 63;
    const int r = lane & 15;          // MFMA operand: m/n index = lane&15
    const int q = lane >> 4;          // k = q*8 + j
    const int wm = (wave >> 2) * 128; // 2 M-waves
    const int wn = (wave & 3) * 64;   // 4 N-waves

    // Bijective XCD swizzle (m204): consecutive seq on the same XCD.
    const int nwg = gridDim.x;
    const int q8 = nwg >> 3, r8 = nwg & 7;
    const int xcd = blockIdx.x & 7, seq = blockIdx.x >> 3;
    const int swz = (xcd < r8 ? xcd * (q8 + 1)
                              : r8 * (q8 + 1) + (xcd - r8) * q8) + seq;
    const int nTiles = N / BN;
    const int row0 = (swz / nTiles) * BM;
    const int col0 = (swz % nTiles) * BN;

    const size_t rowB = (size_t)K * sizeof(__bf16);

    // Staging: thread handles phys byte p=(it*512+tid)*16 of a 16 KiB
    // half-tile (128 rows x 128 B).  Global src = deswizzle(p).
    const char* srcA[2];
    const char* srcB[2];
#pragma unroll
    for (int it = 0; it < 2; ++it) {
        const int p   = (it * 512 + tid) * 16;
        const int lin = p ^ (((p >> 7) & 7) << 4);
        const int gr  = lin >> 7;     // row within half-tile
        const int gc  = lin & 127;    // byte within row
        srcA[it] = (const char*)A + (size_t)(row0 + gr) * rowB + gc;
        srcB[it] = (const char*)B + (size_t)(col0 + gr) * rowB + gc;
    }

#define STAGE(mat, buf, ht, kb) do {                                         \
        async_load16(src##mat[0] + (size_t)(ht) * 128 * rowB + (kb),         \
            ldsb + REG##mat + (buf) * 32768 + (ht) * 16384 + wave * 1024);   \
        async_load16(src##mat[1] + (size_t)(ht) * 128 * rowB + (kb),         \
            ldsb + REG##mat + (buf) * 32768 + (ht) * 16384 + 8192 + wave * 1024); \
    } while (0)

    // Fragment-read swizzled offsets: row&7 == r&7 (wm, m*16 are mult of 8).
    const int sb0 = (q ^ (r & 7)) * 16;        // ks=0 slot
    const int sb1 = ((4 + q) ^ (r & 7)) * 16;  // ks=1 slot
    const int aBase = REGA + (wm + r) * 128;
    const int bBase = REGB + (wn + r) * 128;

    bf16x8 afr[8][2];   // ALL 8 m-frags (front-loaded), 2 k-slices
    bf16x8 bfr[4][2];   // all 4 n-frags, 2 k-slices
    f32x4  acc[8][4];
    const f32x4 zero = {0.f, 0.f, 0.f, 0.f};
#pragma unroll
    for (int i = 0; i < 8; ++i)
#pragma unroll
        for (int j = 0; j < 4; ++j) acc[i][j] = zero;

#define LDA4(buf, mb) do { _Pragma("unroll")                                 \
        for (int mm = 0; mm < 4; ++mm) {                                     \
            const char* pa = ldsb + (buf) * 32768 + aBase + ((mb) + mm) * 2048; \
            afr[(mb) + mm][0] = *(const bf16x8*)(pa + sb0);                  \
            afr[(mb) + mm][1] = *(const bf16x8*)(pa + sb1);                  \
        } } while (0)

#define LDB2(buf, nb) do { _Pragma("unroll")                                 \
        for (int nn = 0; nn < 2; ++nn) {                                     \
            const char* pb = ldsb + (buf) * 32768 + bBase + ((nb) + nn) * 2048; \
            bfr[(nb) + nn][0] = *(const bf16x8*)(pb + sb0);                  \
            bfr[(nb) + nn][1] = *(const bf16x8*)(pb + sb1);                  \
        } } while (0)

#define QUAD(mb, nb) do { _Pragma("unroll")                                  \
        for (int mm = 0; mm < 4; ++mm) { _Pragma("unroll")                   \
        for (int nn = 0; nn < 2; ++nn) { _Pragma("unroll")                   \
        for (int ks = 0; ks < 2; ++ks)                                       \
            acc[(mb) + mm][(nb) + nn] = __builtin_amdgcn_mfma_f32_16x16x32_bf16( \
                afr[(mb) + mm][ks], bfr[(nb) + nn][ks], acc[(mb) + mm][(nb) + nn], 0, 0, 0); \
        } } } while (0)

    // Prologue: Kt0 (8 loads) + Kt1.A (4 loads).  vmcnt(4) drains exactly
    // Kt0, keeps Kt1.A in flight -> matches steady state at loop P0.
    STAGE(A, 0, 0, 0);   STAGE(A, 0, 1, 0);
    STAGE(B, 0, 0, 0);   STAGE(B, 0, 1, 0);
    STAGE(A, 1, 0, 128); STAGE(A, 1, 1, 128);
    VMCNT4();
    BARRIER();

    const int nIter = K >> 7;   // 2 K-tiles per iteration
    for (int i = 0; i < nIter; ++i) {
        const int k0 = i << 7;
        const size_t kb1 = (size_t)(k0 + 64) * 2;
        int k2 = k0 + 128; if (k2 >= K) k2 -= K;
        int k3 = k0 + 192; if (k3 >= K) k3 -= K;
        const size_t kb2 = (size_t)k2 * 2;
        const size_t kb3 = (size_t)k3 * 2;

        // ---- P0  (12 rd; stage buf1.B0)
        LDA4(0, 0); LDB2(0, 0);
        STAGE(B, 1, 0, kb1);
        LGKM8();
        BARRIER(); LGKM0();
        PRIO1(); QUAD(0, 0); PRIO0();
        BARRIER();
        // ---- P1  (8 rd; stage buf1.B1)
        LDA4(0, 4);
        STAGE(B, 1, 1, kb1);
        BARRIER(); LGKM0();
        PRIO1(); QUAD(4, 0); PRIO0();
        BARRIER();
        // ---- P2  (4 rd; stage buf0.A0 -- buf0.A dead since P1)
        LDB2(0, 2);
        STAGE(A, 0, 0, kb2);
        BARRIER(); LGKM0();
        PRIO1(); QUAD(0, 2); PRIO0();
        BARRIER();
        // ---- P3  (0 rd; stage buf0.A1; fence Kt2i+1 before P4 reads buf1)
        STAGE(A, 0, 1, kb2);
        BARRIER();
        PRIO1(); QUAD(4, 2); PRIO0();
        VMCNT4();
        BARRIER();
        // ---- P4  (12 rd; stage buf0.B0 -- buf0.B dead since P2)
        LDA4(1, 0); LDB2(1, 0);
        STAGE(B, 0, 0, kb2);
        LGKM8();
        BARRIER(); LGKM0();
        PRIO1(); QUAD(0, 0); PRIO0();
        BARRIER();
        // ---- P5  (8 rd; stage buf0.B1)
        LDA4(1, 4);
        STAGE(B, 0, 1, kb2);
        BARRIER(); LGKM0();
        PRIO1(); QUAD(4, 0); PRIO0();
        BARRIER();
        // ---- P6  (4 rd; stage buf1.A0 -- buf1.A dead since P5)
        LDB2(1, 2);
        STAGE(A, 1, 0, kb3);
        BARRIER(); LGKM0();
        PRIO1(); QUAD(0, 2); PRIO0();
        BARRIER();
        // ---- P7  (0 rd; stage buf1.A1; fence Kt2i+2 before next-P0 reads buf0)
        STAGE(A, 1, 1, kb3);
        BARRIER();
        PRIO1(); QUAD(4, 2); PRIO0();
        VMCNT4();
        BARRIER();
    }

    // Drain in-flight LDS-DMA before wave exit (successor workgroup reuses
    // this LDS allocation).
    VMCNT0();

    // Epilogue: C/D layout col=lane&15, row=(lane>>4)*4+reg (m89/m91).
#pragma unroll
    for (int n = 0; n < 4; ++n) {
        const int col = col0 + wn + n * 16 + r;
        const float bv = bias[col];
#pragma unroll
        for (int m = 0; m < 8; ++m) {
            const int row = row0 + wm + m * 16 + q * 4;
#pragma unroll
            for (int e = 0; e < 4; ++e)
                C[(size_t)(row + e) * N + col] = acc[m][n][e] + bv;
        }
    }
}

// ------------------------------------------------------- fallback (safety net)
__global__ void fallback_kernel(
    const float* __restrict__ x, const int* __restrict__ wq,
    const float* __restrict__ sc, const float* __restrict__ bias,
    float* __restrict__ out, int T, int O, int I) {
    int o = blockIdx.x * 16 + threadIdx.x;
    int t = blockIdx.y * 16 + threadIdx.y;
    if (o >= O || t >= T) return;
    const int nb = I >> 5;
    float s = 0.f;
    for (int b = 0; b < nb; ++b) {
        const float scv = sc[o * nb + b];
        float p = 0.f;
        for (int k = 0; k < 32; ++k)
            p += x[(size_t)t * I + b * 32 + k] *
                 (float)(wq[(size_t)o * I + b * 32 + k] - 128);
        s += scv * p;
    }
    out[(size_t)t * O + o] = s + bias[o];
}

// ---------------------------------------------------------------------- launch
extern "C" void kernel_launch(void* const* d_in, const int* in_sizes, int n_in,
                              void* d_out, int out_size, void* d_ws, size_t ws_size,
                              hipStream_t stream) {
    const float* x    = (const float*)d_in[0];
    const int*   wq   = (const int*)d_in[1];
    const float* sc   = (const float*)d_in[2];
    const float* bias = (const float*)d_in[3];
    float* out = (float*)d_out;

    const long long xn = in_sizes[0];
    const long long wn = in_sizes[1];
    const int O = in_sizes[3];
    const int I = (int)(wn / O);
    const int T = (int)(xn / I);

    const size_t xbBytes = (size_t)T * I * sizeof(__bf16);
    const size_t wbBytes = (size_t)O * I * sizeof(__bf16);

    const bool fast = (ws_size >= xbBytes + wbBytes) &&
                      (T % BM == 0) && (O % BN == 0) && (I % 1024 == 0) &&
                      (((long long)T * I) % 1024 == 0);

    if (!fast) {
        dim3 blk(16, 16);
        dim3 grd((O + 15) / 16, (T + 15) / 16);
        hipLaunchKernelGGL(fallback_kernel, grd, blk, 0, stream,
                           x, wq, sc, bias, out, T, O, I);
        return;
    }

    __bf16* xb = (__bf16*)d_ws;
    __bf16* wb = (__bf16*)((char*)d_ws + xbBytes);

    {
        const int n4 = (int)((long long)T * I / 4);
        hipLaunchKernelGGL(prep_x, dim3((n4 + 255) / 256), dim3(256), 0, stream,
                           x, xb, n4);
        hipLaunchKernelGGL(prep_w, dim3(I / 1024, O), dim3(256), 0, stream,
                           wq, sc, wb, I);
    }
    const int nwg = (T / BM) * (O / BN);
    hipLaunchKernelGGL(gemm_8phase, dim3(nwg), dim3(512), 0, stream,
                       xb, wb, bias, out, T, O, I);
}

// Round 5
// 489.714 us; speedup vs baseline: 1.0560x; 1.0560x over previous
//
#include <hip/hip_runtime.h>

using bf16x8 = __attribute__((ext_vector_type(8))) __bf16;
using bf16x4 = __attribute__((ext_vector_type(4))) __bf16;
using f32x4  = __attribute__((ext_vector_type(4))) float;

#define BM 256
#define BN 256

// Async global->LDS, 16B per lane. LDS dest is wave-uniform base + lane*16
// (m104/m108): pass the wave's base, per-lane global src.
__device__ __forceinline__ void async_load16(const void* g, void* l) {
    __builtin_amdgcn_global_load_lds(
        (const __attribute__((address_space(1))) unsigned int*)g,
        (__attribute__((address_space(3))) unsigned int*)l,
        16, 0, 0);
}

// ------------------------------------------------------------- prep kernels
// prep_x: fp32 -> bf16, unit-stride float4 per lane (16B load, 8B store).
__global__ __launch_bounds__(256) void prep_x(
    const float* __restrict__ x, __bf16* __restrict__ xb, int n4) {
    const int c = blockIdx.x * 256 + threadIdx.x;
    if (c >= n4) return;
    const float4 a = ((const float4*)x)[c];
    bf16x4 v;
    v[0] = (__bf16)a.x; v[1] = (__bf16)a.y; v[2] = (__bf16)a.z; v[3] = (__bf16)a.w;
    ((bf16x4*)xb)[c] = v;
}

// prep_w: int32 quant -> (q-128)*scale -> bf16.  2D grid: row = blockIdx.y
// (no integer division), unit-stride int4 per lane.
__global__ __launch_bounds__(256) void prep_w(
    const int* __restrict__ wq, const float* __restrict__ sc,
    __bf16* __restrict__ wb, int I) {
    const int row = blockIdx.y;
    const int c = blockIdx.x * 256 + threadIdx.x;   // [0, I/4)
    const size_t base = (size_t)row * I + (size_t)c * 4;
    const float s = sc[row * (I >> 5) + (c >> 3)];
    const int4 a = *(const int4*)(wq + base);
    bf16x4 v;
    v[0] = (__bf16)((float)(a.x - 128) * s);
    v[1] = (__bf16)((float)(a.y - 128) * s);
    v[2] = (__bf16)((float)(a.z - 128) * s);
    v[3] = (__bf16)((float)(a.w - 128) * s);
    *(bf16x4*)(wb + base) = v;
}

// ---------------------------------------------------------------- main GEMM
// C[M,N] = A[M,K]*B[N,K]^T + bias[N].  256x256 tile, BK=64, 8 waves (2Mx4N),
// 8-phase schedule (T3+T4), st-swizzled LDS (T2), setprio (T5), XCD swz (T1).
//
// This is the ROUND-2 schedule (proven 253 us / 47% MfmaUtil / 0 bank
// conflicts) with ONE change: stage->phase mapping re-timed to
// earliest-safe, deepening the fence from vmcnt(2) (1-phase slack) to
// vmcnt(4) (>=2-phase slack per half-tile).  Reads/QUAD order untouched.
//
// LDS (128 KiB): A tiles [2][256][64]bf16 at byte 0, B tiles at byte 65536.
// Swizzle: phys = lin ^ (((lin>>7)&7)<<4) (involution, 16B-chunk
// preserving; verified 0 conflicts in R2).  gload_lds writes LINEAR phys;
// per-lane GLOBAL src pre-deswizzled (rule 21).
//
// Per iteration = 2 K-tiles: buf0 = Kt(2i) [k0] phases 0-3, buf1 =
// Kt(2i+1) [k0+64] phases 4-7.  Reads (R2 pattern):
//   P0: a[m0-3]+b[n0-1] (12 rd)  QUAD(0,0)     P4: same on buf1
//   P1: b[n2-3]          (4 rd)  QUAD(0,2)     P5: ...
//   P2: a[m4-7]          (8 rd)  QUAD(4,2)     P6: ...
//   P3: (none)                   QUAD(4,0)     P7: ...
// Region deaths: buf.B dead after P1(P5); buf.A dead after P2(P6).
// Stages (1 half-tile = 2 gload_lds per phase, earliest-safe):
//   P0: buf1.A0@k0+64   (buf1.A dead since prev-P6)
//   P1: buf1.A1@k0+64
//   P2: buf0.B0@k0+128  (buf0.B dead since P1)
//   P3: buf0.B1@k0+128
//   P4: buf0.A0@k0+128  (buf0.A dead since P2)
//   P5: buf0.A1@k0+128
//   P6: buf1.B0@k0+192  (buf1.B dead since P5)
//   P7: buf1.B1@k0+192
// Fences vmcnt(4), after QUAD, at P3 and P7 only:
//   P3: outstanding = prevP6,prevP7(buf1.B@k0+64) + P0,P1(buf1.A) +
//       P2,P3(buf0.B) = 12; drain oldest 8 = buf1 complete before P4.
//       Youngest-drained (P1) has 2-phase slack.
//   P7: outstanding = P2..P7 = 12; drain oldest 8 = P2..P5 = buf0
//       complete before next-P0.  Youngest-drained (P5) 2-phase slack.
// Never drained to 0 in-loop.  Tail stages wrap k mod K (in-bounds, data
// unused).  Post-loop vmcnt(0) before s_endpgm (in-flight LDS-DMA at wave
// exit corrupts successor WG's LDS).
#define REGA 0
#define REGB 65536

#define BARRIER()  __builtin_amdgcn_s_barrier()
#define LGKM0()    asm volatile("s_waitcnt lgkmcnt(0)" ::: "memory")
#define VMCNT4()   asm volatile("s_waitcnt vmcnt(4)" ::: "memory")
#define VMCNT0()   asm volatile("s_waitcnt vmcnt(0)" ::: "memory")
#define PRIO1()    __builtin_amdgcn_s_setprio(1)
#define PRIO0()    __builtin_amdgcn_s_setprio(0)

__global__ __launch_bounds__(512, 2) void gemm_8phase(
    const __bf16* __restrict__ A, const __bf16* __restrict__ B,
    const float* __restrict__ bias, float* __restrict__ C,
    int M, int N, int K) {
    __shared__ char lds[131072] __attribute__((aligned(16)));
    char* const ldsb = lds;

    const int tid  = threadIdx.x;
    const int wave = tid >> 6;
    const int lane = tid & 63;
    const int r = lane & 15;          // MFMA operand: m/n index = lane&15
    const int q = lane >> 4;          // k = q*8 + j
    const int wm = (wave >> 2) * 128; // 2 M-waves
    const int wn = (wave & 3) * 64;   // 4 N-waves

    // Bijective XCD swizzle (m204): consecutive seq on the same XCD.
    const int nwg = gridDim.x;
    const int q8 = nwg >> 3, r8 = nwg & 7;
    const int xcd = blockIdx.x & 7, seq = blockIdx.x >> 3;
    const int swz = (xcd < r8 ? xcd * (q8 + 1)
                              : r8 * (q8 + 1) + (xcd - r8) * q8) + seq;
    const int nTiles = N / BN;
    const int row0 = (swz / nTiles) * BM;
    const int col0 = (swz % nTiles) * BN;

    const size_t rowB = (size_t)K * sizeof(__bf16);

    // Staging: thread handles phys byte p=(it*512+tid)*16 of a 16 KiB
    // half-tile (128 rows x 128 B).  Global src = deswizzle(p).
    const char* srcA[2];
    const char* srcB[2];
#pragma unroll
    for (int it = 0; it < 2; ++it) {
        const int p   = (it * 512 + tid) * 16;
        const int lin = p ^ (((p >> 7) & 7) << 4);
        const int gr  = lin >> 7;     // row within half-tile
        const int gc  = lin & 127;    // byte within row
        srcA[it] = (const char*)A + (size_t)(row0 + gr) * rowB + gc;
        srcB[it] = (const char*)B + (size_t)(col0 + gr) * rowB + gc;
    }

#define STAGE(mat, buf, ht, kb) do {                                         \
        async_load16(src##mat[0] + (size_t)(ht) * 128 * rowB + (kb),         \
            ldsb + REG##mat + (buf) * 32768 + (ht) * 16384 + wave * 1024);   \
        async_load16(src##mat[1] + (size_t)(ht) * 128 * rowB + (kb),         \
            ldsb + REG##mat + (buf) * 32768 + (ht) * 16384 + 8192 + wave * 1024); \
    } while (0)

    // Fragment-read swizzled offsets: row&7 == r&7 (wm, m*16 are mult of 8).
    const int sb0 = (q ^ (r & 7)) * 16;        // ks=0 slot
    const int sb1 = ((4 + q) ^ (r & 7)) * 16;  // ks=1 slot
    const int aBase = REGA + (wm + r) * 128;
    const int bBase = REGB + (wn + r) * 128;

    bf16x8 afr[4][2];   // current m-half, 2 k-slices (R2 footprint)
    bf16x8 bfr[4][2];   // all 4 n-frags, 2 k-slices
    f32x4  acc[8][4];
    const f32x4 zero = {0.f, 0.f, 0.f, 0.f};
#pragma unroll
    for (int i = 0; i < 8; ++i)
#pragma unroll
        for (int j = 0; j < 4; ++j) acc[i][j] = zero;

#define LDA4(buf, mb) do { _Pragma("unroll")                                 \
        for (int mm = 0; mm < 4; ++mm) {                                     \
            const char* pa = ldsb + (buf) * 32768 + aBase + ((mb) + mm) * 2048; \
            afr[mm][0] = *(const bf16x8*)(pa + sb0);                         \
            afr[mm][1] = *(const bf16x8*)(pa + sb1);                         \
        } } while (0)

#define LDB2(buf, nb) do { _Pragma("unroll")                                 \
        for (int nn = 0; nn < 2; ++nn) {                                     \
            const char* pb = ldsb + (buf) * 32768 + bBase + ((nb) + nn) * 2048; \
            bfr[(nb) + nn][0] = *(const bf16x8*)(pb + sb0);                  \
            bfr[(nb) + nn][1] = *(const bf16x8*)(pb + sb1);                  \
        } } while (0)

#define QUAD(mb, nb) do { _Pragma("unroll")                                  \
        for (int mm = 0; mm < 4; ++mm) { _Pragma("unroll")                   \
        for (int nn = 0; nn < 2; ++nn) { _Pragma("unroll")                   \
        for (int ks = 0; ks < 2; ++ks)                                       \
            acc[(mb) + mm][(nb) + nn] = __builtin_amdgcn_mfma_f32_16x16x32_bf16( \
                afr[mm][ks], bfr[(nb) + nn][ks], acc[(mb) + mm][(nb) + nn], 0, 0, 0); \
        } } } while (0)

    // Prologue: buf0 = Kt0 complete (8 loads) + buf1.B@k=64 (4 loads).
    // vmcnt(4) drains exactly Kt0, keeps buf1.B in flight -- matches the
    // steady-state precondition at loop P0 (in-flight = prev-P6,P7).
    STAGE(A, 0, 0, 0);  STAGE(A, 0, 1, 0);
    STAGE(B, 0, 0, 0);  STAGE(B, 0, 1, 0);
    STAGE(B, 1, 0, 128); STAGE(B, 1, 1, 128);
    VMCNT4();
    BARRIER();

    const int nIter = K >> 7;   // 2 K-tiles per iteration
    for (int i = 0; i < nIter; ++i) {
        const int k0 = i << 7;
        const size_t kb1 = (size_t)(k0 + 64) * 2;
        int k2 = k0 + 128; if (k2 >= K) k2 -= K;
        int k3 = k0 + 192; if (k3 >= K) k3 -= K;
        const size_t kb2 = (size_t)k2 * 2;
        const size_t kb3 = (size_t)k3 * 2;

        // ---- P0  (12 rd; stage buf1.A0@k0+64 -- buf1.A dead since prev-P6)
        LDA4(0, 0); LDB2(0, 0);
        STAGE(A, 1, 0, kb1);
        BARRIER(); LGKM0();
        PRIO1(); QUAD(0, 0); PRIO0();
        BARRIER();
        // ---- P1  (4 rd; stage buf1.A1@k0+64)
        LDB2(0, 2);
        STAGE(A, 1, 1, kb1);
        BARRIER(); LGKM0();
        PRIO1(); QUAD(0, 2); PRIO0();
        BARRIER();
        // ---- P2  (8 rd; stage buf0.B0@k0+128 -- buf0.B dead since P1)
        LDA4(0, 4);
        STAGE(B, 0, 0, kb2);
        BARRIER(); LGKM0();
        PRIO1(); QUAD(4, 2); PRIO0();
        BARRIER();
        // ---- P3  (0 rd; stage buf0.B1@k0+128; fence buf1 before P4)
        STAGE(B, 0, 1, kb2);
        BARRIER(); LGKM0();
        PRIO1(); QUAD(4, 0); PRIO0();
        VMCNT4();
        BARRIER();
        // ---- P4  (12 rd; stage buf0.A0@k0+128 -- buf0.A dead since P2)
        LDA4(1, 0); LDB2(1, 0);
        STAGE(A, 0, 0, kb2);
        BARRIER(); LGKM0();
        PRIO1(); QUAD(0, 0); PRIO0();
        BARRIER();
        // ---- P5  (4 rd; stage buf0.A1@k0+128)
        LDB2(1, 2);
        STAGE(A, 0, 1, kb2);
        BARRIER(); LGKM0();
        PRIO1(); QUAD(0, 2); PRIO0();
        BARRIER();
        // ---- P6  (8 rd; stage buf1.B0@k0+192 -- buf1.B dead since P5)
        LDA4(1, 4);
        STAGE(B, 1, 0, kb3);
        BARRIER(); LGKM0();
        PRIO1(); QUAD(4, 2); PRIO0();
        BARRIER();
        // ---- P7  (0 rd; stage buf1.B1@k0+192; fence buf0 before next-P0)
        STAGE(B, 1, 1, kb3);
        BARRIER(); LGKM0();
        PRIO1(); QUAD(4, 0); PRIO0();
        VMCNT4();
        BARRIER();
    }

    // Drain in-flight LDS-DMA before wave exit (successor workgroup reuses
    // this LDS allocation).
    VMCNT0();

    // Epilogue: C/D layout col=lane&15, row=(lane>>4)*4+reg (m89/m91).
#pragma unroll
    for (int n = 0; n < 4; ++n) {
        const int col = col0 + wn + n * 16 + r;
        const float bv = bias[col];
#pragma unroll
        for (int m = 0; m < 8; ++m) {
            const int row = row0 + wm + m * 16 + q * 4;
#pragma unroll
            for (int e = 0; e < 4; ++e)
                C[(size_t)(row + e) * N + col] = acc[m][n][e] + bv;
        }
    }
}

// ------------------------------------------------------- fallback (safety net)
__global__ void fallback_kernel(
    const float* __restrict__ x, const int* __restrict__ wq,
    const float* __restrict__ sc, const float* __restrict__ bias,
    float* __restrict__ out, int T, int O, int I) {
    int o = blockIdx.x * 16 + threadIdx.x;
    int t = blockIdx.y * 16 + threadIdx.y;
    if (o >= O || t >= T) return;
    const int nb = I >> 5;
    float s = 0.f;
    for (int b = 0; b < nb; ++b) {
        const float scv = sc[o * nb + b];
        float p = 0.f;
        for (int k = 0; k < 32; ++k)
            p += x[(size_t)t * I + b * 32 + k] *
                 (float)(wq[(size_t)o * I + b * 32 + k] - 128);
        s += scv * p;
    }
    out[(size_t)t * O + o] = s + bias[o];
}

// ---------------------------------------------------------------------- launch
extern "C" void kernel_launch(void* const* d_in, const int* in_sizes, int n_in,
                              void* d_out, int out_size, void* d_ws, size_t ws_size,
                              hipStream_t stream) {
    const float* x    = (const float*)d_in[0];
    const int*   wq   = (const int*)d_in[1];
    const float* sc   = (const float*)d_in[2];
    const float* bias = (const float*)d_in[3];
    float* out = (float*)d_out;

    const long long xn = in_sizes[0];
    const long long wn = in_sizes[1];
    const int O = in_sizes[3];
    const int I = (int)(wn / O);
    const int T = (int)(xn / I);

    const size_t xbBytes = (size_t)T * I * sizeof(__bf16);
    const size_t wbBytes = (size_t)O * I * sizeof(__bf16);

    const bool fast = (ws_size >= xbBytes + wbBytes) &&
                      (T % BM == 0) && (O % BN == 0) && (I % 1024 == 0) &&
                      (((long long)T * I) % 1024 == 0);

    if (!fast) {
        dim3 blk(16, 16);
        dim3 grd((O + 15) / 16, (T + 15) / 16);
        hipLaunchKernelGGL(fallback_kernel, grd, blk, 0, stream,
                           x, wq, sc, bias, out, T, O, I);
        return;
    }

    __bf16* xb = (__bf16*)d_ws;
    __bf16* wb = (__bf16*)((char*)d_ws + xbBytes);

    {
        const int n4 = (int)((long long)T * I / 4);
        hipLaunchKernelGGL(prep_x, dim3((n4 + 255) / 256), dim3(256), 0, stream,
                           x, xb, n4);
        hipLaunchKernelGGL(prep_w, dim3(I / 1024, O), dim3(256), 0, stream,
                           wq, sc, wb, I);
    }
    const int nwg = (T / BM) * (O / BN);
    hipLaunchKernelGGL(gemm_8phase, dim3(nwg), dim3(512), 0, stream,
                       xb, wb, bias, out, T, O, I);
}